// Round 1
// baseline (1749.841 us; speedup 1.0000x reference)
//
#include <hip/hip_runtime.h>

#define C 2048
#define NODE 1024
#define H 8

static __device__ __forceinline__ float wave_reduce_sum(float v) {
  #pragma unroll
  for (int off = 32; off; off >>= 1) v += __shfl_down(v, off, 64);
  return v;
}
static __device__ __forceinline__ float wave_reduce_max(float v) {
  #pragma unroll
  for (int off = 32; off; off >>= 1) v = fmaxf(v, __shfl_down(v, off, 64));
  return v;
}

// obs_mean[i] = relu(Wo1[i,:] + bo1) . Wo2 + bo2   (one wave per row)
__global__ void k_obsmean(const float* __restrict__ Wo1, const float* __restrict__ bo1,
                          const float* __restrict__ Wo2, const float* __restrict__ bo2,
                          float* __restrict__ obs_mean) {
  int row = blockIdx.x * 4 + (threadIdx.x >> 6);
  int lane = threadIdx.x & 63;
  const float* wr = Wo1 + (size_t)row * NODE;
  float acc = 0.f;
  for (int n = lane; n < NODE; n += 64)
    acc += fmaxf(wr[n] + bo1[n], 0.f) * Wo2[n];
  acc = wave_reduce_sum(acc);
  if (lane == 0) obs_mean[row] = acc + bo2[0];
}

// hidden[n] = relu([bel, a, o] . Wb1[:,n] + bb1[n])
__global__ void k_hidden_b(const float* __restrict__ bel_prev,
                           const float* __restrict__ actions, const float* __restrict__ obs,
                           int s,
                           const float* __restrict__ Wb1, const float* __restrict__ bb1,
                           float* __restrict__ hidden) {
  __shared__ float sb[C];
  int t = threadIdx.x;
  for (int k = t; k < C; k += 256) sb[k] = bel_prev[k];
  __syncthreads();
  int n = blockIdx.x * 256 + t;
  float acc = bb1[n];
  #pragma unroll 8
  for (int k = 0; k < C; ++k) acc = fmaf(sb[k], Wb1[(size_t)k * NODE + n], acc);
  acc = fmaf(actions[s], Wb1[(size_t)C * NODE + n], acc);
  acc = fmaf(obs[s],     Wb1[(size_t)(C + 1) * NODE + n], acc);
  hidden[n] = fmaxf(acc, 0.f);
}

// logits[j] = hidden . Wb2[:,j] + bb2[j]
__global__ void k_logits_b(const float* __restrict__ hidden,
                           const float* __restrict__ Wb2, const float* __restrict__ bb2,
                           float* __restrict__ logits) {
  __shared__ float sh[NODE];
  int t = threadIdx.x;
  for (int n = t; n < NODE; n += 256) sh[n] = hidden[n];
  __syncthreads();
  int j = blockIdx.x * 256 + t;
  float acc = bb2[j];
  #pragma unroll 8
  for (int n = 0; n < NODE; ++n) acc = fmaf(sh[n], Wb2[(size_t)n * C + j], acc);
  logits[j] = acc;
}

__global__ void k_softmax_b(const float* __restrict__ logits, float* __restrict__ belief) {
  __shared__ float red[4];
  __shared__ float redz[4];
  int t = threadIdx.x, w = t >> 6, lane = t & 63;
  float m = -3.4e38f;
  for (int j = t; j < C; j += 256) m = fmaxf(m, logits[j]);
  m = wave_reduce_max(m);
  if (lane == 0) red[w] = m;
  __syncthreads();
  m = fmaxf(fmaxf(red[0], red[1]), fmaxf(red[2], red[3]));
  float z = 0.f;
  for (int j = t; j < C; j += 256) z += expf(logits[j] - m);
  z = wave_reduce_sum(z);
  if (lane == 0) redz[w] = z;
  __syncthreads();
  z = redz[0] + redz[1] + redz[2] + redz[3];
  float inv = 1.f / z;
  for (int j = t; j < C; j += 256) belief[j] = expf(logits[j] - m) * inv;
}

// logits_t for rows of group steps [s0, s0+gg): out[(r)*C + c], r group-local.
// A is generated on the fly: hidden[i,n] = relu(Wt1[i,n] + a_s*Wt1[C,n] + bt1[n])
__global__ __launch_bounds__(256) void k_trans_gemm(
    const float* __restrict__ Wt1, const float* __restrict__ bt1,
    const float* __restrict__ Wt2, const float* __restrict__ bt2,
    const float* __restrict__ actions, int s0, float* __restrict__ out) {
  __shared__ float As[32][132];   // As[k][row]
  __shared__ float Bs[32][132];   // Bs[k][col]
  int tid = threadIdx.x;
  int r0g = blockIdx.y * 128;               // group-local row base (step-uniform: 2048%128==0)
  int s = s0 + (r0g >> 11);
  int i0 = r0g & (C - 1);
  int c0 = blockIdx.x * 128;
  float a_s = actions[s];
  float acc[8][8];
  #pragma unroll
  for (int y = 0; y < 8; ++y)
    #pragma unroll
    for (int x = 0; x < 8; ++x) acc[y][x] = 0.f;
  int tx = tid & 15, ty = tid >> 4;

  for (int k0 = 0; k0 < NODE; k0 += 32) {
    #pragma unroll
    for (int p = 0; p < 4; ++p) {           // stage A: 128 rows x 32 k
      int idx = p * 256 + tid;
      int ri = idx >> 3;
      int kk = (idx & 7) << 2;
      float4 wv = *(const float4*)&Wt1[(size_t)(i0 + ri) * NODE + k0 + kk];
      float4 wa = *(const float4*)&Wt1[(size_t)C * NODE + k0 + kk];
      float4 bv = *(const float4*)&bt1[k0 + kk];
      As[kk + 0][ri] = fmaxf(fmaf(a_s, wa.x, wv.x) + bv.x, 0.f);
      As[kk + 1][ri] = fmaxf(fmaf(a_s, wa.y, wv.y) + bv.y, 0.f);
      As[kk + 2][ri] = fmaxf(fmaf(a_s, wa.z, wv.z) + bv.z, 0.f);
      As[kk + 3][ri] = fmaxf(fmaf(a_s, wa.w, wv.w) + bv.w, 0.f);
    }
    #pragma unroll
    for (int p = 0; p < 4; ++p) {           // stage B: 32 k x 128 cols
      int idx = p * 256 + tid;
      int kk = idx >> 5;
      int c4 = (idx & 31) << 2;
      *(float4*)&Bs[kk][c4] = *(const float4*)&Wt2[(size_t)(k0 + kk) * C + c0 + c4];
    }
    __syncthreads();
    #pragma unroll 8
    for (int kk = 0; kk < 32; ++kk) {
      float av[8], bv[8];
      *(float4*)&av[0] = *(const float4*)&As[kk][ty * 8];
      *(float4*)&av[4] = *(const float4*)&As[kk][ty * 8 + 4];
      *(float4*)&bv[0] = *(const float4*)&Bs[kk][tx * 8];
      *(float4*)&bv[4] = *(const float4*)&Bs[kk][tx * 8 + 4];
      #pragma unroll
      for (int y = 0; y < 8; ++y)
        #pragma unroll
        for (int x = 0; x < 8; ++x) acc[y][x] = fmaf(av[y], bv[x], acc[y][x]);
    }
    __syncthreads();
  }
  #pragma unroll
  for (int y = 0; y < 8; ++y) {
    int row = r0g + ty * 8 + y;
    size_t base = (size_t)row * C + c0 + tx * 8;
    float4 v0, v1;
    v0.x = acc[y][0] + bt2[c0 + tx * 8 + 0];
    v0.y = acc[y][1] + bt2[c0 + tx * 8 + 1];
    v0.z = acc[y][2] + bt2[c0 + tx * 8 + 2];
    v0.w = acc[y][3] + bt2[c0 + tx * 8 + 3];
    v1.x = acc[y][4] + bt2[c0 + tx * 8 + 4];
    v1.y = acc[y][5] + bt2[c0 + tx * 8 + 5];
    v1.z = acc[y][6] + bt2[c0 + tx * 8 + 6];
    v1.w = acc[y][7] + bt2[c0 + tx * 8 + 7];
    *(float4*)&out[base] = v0;
    *(float4*)&out[base + 4] = v1;
  }
}

// per row: m = max_j l, Z = sum exp(l-m); store m and w = belief_{s-1}[i]/Z
__global__ void k_rowstats(const float* __restrict__ logits, const float* __restrict__ beliefs,
                           int s0, float* __restrict__ rowm, float* __restrict__ roww) {
  int r = blockIdx.x * 4 + (threadIdx.x >> 6);   // group-local row
  int lane = threadIdx.x & 63;
  int s = s0 + (r >> 11);
  int i = r & (C - 1);
  const float* lr = logits + (size_t)r * C;
  float m = -3.4e38f;
  for (int j = lane; j < C; j += 64) m = fmaxf(m, lr[j]);
  m = wave_reduce_max(m);
  m = __shfl(m, 0, 64);
  float z = 0.f;
  for (int j = lane; j < C; j += 64) z += expf(lr[j] - m);
  z = wave_reduce_sum(z);
  if (lane == 0) {
    rowm[(size_t)s * C + i] = m;
    roww[(size_t)s * C + i] = beliefs[(size_t)s * C + i] / z;
  }
}

// partial pred over a 256-row chunk: partial[(s*8+itile)*C + j] = sum_i w_i exp(l[i][j]-m_i)
__global__ void k_pred_partial(const float* __restrict__ logits,
                               const float* __restrict__ rowm, const float* __restrict__ roww,
                               int s0, float* __restrict__ partial) {
  int t = threadIdx.x;
  int sl = blockIdx.z;
  int s = s0 + sl;
  int j = blockIdx.x * 256 + t;
  int i0 = blockIdx.y * 256;
  __shared__ float sm[256], sw[256];
  sm[t] = rowm[(size_t)s * C + i0 + t];
  sw[t] = roww[(size_t)s * C + i0 + t];
  __syncthreads();
  const float* lp = logits + ((size_t)sl * C + i0) * C + j;
  float acc = 0.f;
  #pragma unroll 4
  for (int ii = 0; ii < 256; ++ii)
    acc += sw[ii] * expf(lp[(size_t)ii * C] - sm[ii]);
  partial[((size_t)s * 8 + blockIdx.y) * C + j] = acc;
}

__global__ void k_pred_reduce(const float* __restrict__ partial, float* __restrict__ pred) {
  int s = blockIdx.x >> 3;
  int j = ((blockIdx.x & 7) << 8) + threadIdx.x;
  float acc = 0.f;
  #pragma unroll
  for (int it = 0; it < 8; ++it) acc += partial[((size_t)s * 8 + it) * C + j];
  pred[(size_t)s * C + j] = acc;
}

// per step: first = -sum_j b*logp ; second = sum_j b*(log b - log pred)
__global__ void k_loss(const float* __restrict__ beliefs, const float* __restrict__ pred,
                       const float* __restrict__ obs_mean, const float* __restrict__ obs,
                       float* __restrict__ loss_out) {
  int s = blockIdx.x, t = threadIdx.x;
  float o = obs[s];
  float f = 0.f, sec = 0.f;
  for (int j = t; j < C; j += 256) {
    float b = beliefs[(size_t)(s + 1) * C + j];
    float d = o - obs_mean[j];
    float logp = -0.5f * d * d - 0.91893853320467274178f;
    f -= b * logp;
    float p = pred[(size_t)s * C + j];
    sec += (b > 0.f) ? b * (logf(b) - logf(p)) : 0.f;
  }
  __shared__ float rf[4], rs[4];
  int w = t >> 6, lane = t & 63;
  f = wave_reduce_sum(f);
  sec = wave_reduce_sum(sec);
  if (lane == 0) { rf[w] = f; rs[w] = sec; }
  __syncthreads();
  if (t == 0) {
    loss_out[s]     = rf[0] + rf[1] + rf[2] + rf[3];
    loss_out[H + s] = rs[0] + rs[1] + rs[2] + rs[3];
  }
}

__global__ void k_final(const float* __restrict__ loss_out, const float* __restrict__ beliefs,
                        float* __restrict__ out) {
  int t = threadIdx.x;
  if (t == 0) {
    float tot = 0.f;
    for (int s = 0; s < H; ++s) tot += loss_out[s] + loss_out[H + s];
    out[0] = tot;
  }
  for (int j = t; j < C; j += 256) out[1 + j] = beliefs[(size_t)H * C + j];
}

extern "C" void kernel_launch(void* const* d_in, const int* in_sizes, int n_in,
                              void* d_out, int out_size, void* d_ws, size_t ws_size,
                              hipStream_t stream) {
  const float* obs        = (const float*)d_in[0];
  const float* actions    = (const float*)d_in[1];
  const float* prev_belief= (const float*)d_in[2];
  const float* Wb1 = (const float*)d_in[3];
  const float* bb1 = (const float*)d_in[4];
  const float* Wb2 = (const float*)d_in[5];
  const float* bb2 = (const float*)d_in[6];
  const float* Wt1 = (const float*)d_in[7];
  const float* bt1 = (const float*)d_in[8];
  const float* Wt2 = (const float*)d_in[9];
  const float* bt2 = (const float*)d_in[10];
  const float* Wo1 = (const float*)d_in[11];
  const float* bo1 = (const float*)d_in[12];
  const float* Wo2 = (const float*)d_in[13];
  const float* bo2 = (const float*)d_in[14];
  float* out = (float*)d_out;

  float* ws       = (float*)d_ws;
  float* obs_mean = ws;                       // C
  float* beliefs  = obs_mean + C;             // (H+1)*C ; beliefs[0]=prev
  float* hidden   = beliefs + (H + 1) * C;    // NODE
  float* logits_b = hidden + NODE;            // C
  float* rowm     = logits_b + C;             // H*C
  float* roww     = rowm + H * C;             // H*C
  float* pred     = roww + H * C;             // H*C
  float* partial  = pred + H * C;             // H*8*C
  float* lossbuf  = partial + (size_t)H * 8 * C; // 2*H (padded to 64)
  float* logits   = lossbuf + 64;             // g*C*C

  size_t used = (size_t)((char*)logits - (char*)ws);
  size_t per_step = (size_t)C * C * sizeof(float);
  int g = (ws_size > used) ? (int)((ws_size - used) / per_step) : 1;
  if (g < 1) g = 1;
  if (g > H) g = H;

  k_obsmean<<<dim3(C / 4), dim3(256), 0, stream>>>(Wo1, bo1, Wo2, bo2, obs_mean);
  hipMemcpyAsync(beliefs, prev_belief, (size_t)C * sizeof(float),
                 hipMemcpyDeviceToDevice, stream);

  for (int s = 0; s < H; ++s) {
    k_hidden_b<<<dim3(NODE / 256), 256, 0, stream>>>(beliefs + (size_t)s * C, actions, obs, s,
                                                     Wb1, bb1, hidden);
    k_logits_b<<<dim3(C / 256), 256, 0, stream>>>(hidden, Wb2, bb2, logits_b);
    k_softmax_b<<<1, 256, 0, stream>>>(logits_b, beliefs + (size_t)(s + 1) * C);
  }

  for (int s0 = 0; s0 < H; s0 += g) {
    int gg = (H - s0 < g) ? (H - s0) : g;
    k_trans_gemm<<<dim3(C / 128, gg * (C / 128)), 256, 0, stream>>>(Wt1, bt1, Wt2, bt2,
                                                                    actions, s0, logits);
    k_rowstats<<<dim3(gg * (C / 4)), 256, 0, stream>>>(logits, beliefs, s0, rowm, roww);
    k_pred_partial<<<dim3(C / 256, C / 256, gg), 256, 0, stream>>>(logits, rowm, roww, s0,
                                                                    partial);
  }
  k_pred_reduce<<<dim3(H * C / 256), 256, 0, stream>>>(partial, pred);
  k_loss<<<dim3(H), 256, 0, stream>>>(beliefs, pred, obs_mean, obs, lossbuf);
  k_final<<<1, 256, 0, stream>>>(lossbuf, beliefs, out);
}

// Round 2
// 489.115 us; speedup vs baseline: 3.5776x; 3.5776x over previous
//
#include <hip/hip_runtime.h>
#include <hip/hip_bf16.h>

#define C 2048
#define NODE 1024
#define H 8

typedef unsigned short u16;
typedef __attribute__((ext_vector_type(8))) short short8;
typedef __attribute__((ext_vector_type(4))) float f32x4;
typedef __attribute__((ext_vector_type(4))) unsigned short u16x4;

static __device__ __forceinline__ float wave_reduce_sum(float v) {
  #pragma unroll
  for (int off = 32; off; off >>= 1) v += __shfl_down(v, off, 64);
  return v;
}
static __device__ __forceinline__ float wave_reduce_max(float v) {
  #pragma unroll
  for (int off = 32; off; off >>= 1) v = fmaxf(v, __shfl_down(v, off, 64));
  return v;
}
static __device__ __forceinline__ u16 f2bf(float x) {
  __hip_bfloat16 h = __float2bfloat16(x);
  return *reinterpret_cast<u16*>(&h);
}
static __device__ __forceinline__ float bf2f(u16 u) {
  unsigned v = ((unsigned)u) << 16;
  return __uint_as_float(v);
}

#define GLOAD_LDS16(g, l)                                                     \
  __builtin_amdgcn_global_load_lds(                                           \
      (const __attribute__((address_space(1))) void*)(g),                     \
      (__attribute__((address_space(3))) void*)(l), 16, 0, 0)

// obs_mean[i] = relu(Wo1[i,:] + bo1) . Wo2 + bo2   (one wave per row)
__global__ void k_obsmean(const float* __restrict__ Wo1, const float* __restrict__ bo1,
                          const float* __restrict__ Wo2, const float* __restrict__ bo2,
                          float* __restrict__ obs_mean) {
  int row = blockIdx.x * 4 + (threadIdx.x >> 6);
  int lane = threadIdx.x & 63;
  const float* wr = Wo1 + (size_t)row * NODE;
  float acc = 0.f;
  for (int n = lane; n < NODE; n += 64)
    acc += fmaxf(wr[n] + bo1[n], 0.f) * Wo2[n];
  acc = wave_reduce_sum(acc);
  if (lane == 0) obs_mean[row] = acc + bo2[0];
}

// ---- belief chain, split-K ----
// hpart[kc][n] = sum over k in [kc*256,(kc+1)*256) of bel[k]*Wb1[k][n]
__global__ void k_hidden_part(const float* __restrict__ bel, const float* __restrict__ Wb1,
                              float* __restrict__ hpart) {
  __shared__ float sb[256];
  int t = threadIdx.x;
  int kc = blockIdx.y;
  sb[t] = bel[kc * 256 + t];
  __syncthreads();
  int n = blockIdx.x * 256 + t;
  const float* wp = Wb1 + (size_t)(kc * 256) * NODE + n;
  float acc = 0.f;
  #pragma unroll 8
  for (int kk = 0; kk < 256; ++kk) acc = fmaf(sb[kk], wp[(size_t)kk * NODE], acc);
  hpart[(size_t)kc * NODE + n] = acc;
}

// finish hidden chunk (sum 8 parts + bias + a,o terms + relu), then partial logits
__global__ void k_logits_part(const float* __restrict__ hpart, const float* __restrict__ Wb1,
                              const float* __restrict__ bb1,
                              const float* __restrict__ actions, const float* __restrict__ obs,
                              int s, const float* __restrict__ Wb2, float* __restrict__ lpart) {
  __shared__ float sh[256];
  int t = threadIdx.x;
  int kc = blockIdx.y;                        // 0..3 over NODE
  int n = kc * 256 + t;
  float hv = bb1[n];
  #pragma unroll
  for (int p = 0; p < 8; ++p) hv += hpart[(size_t)p * NODE + n];
  hv = fmaf(actions[s], Wb1[(size_t)C * NODE + n], hv);
  hv = fmaf(obs[s], Wb1[(size_t)(C + 1) * NODE + n], hv);
  sh[t] = fmaxf(hv, 0.f);
  __syncthreads();
  int j = blockIdx.x * 256 + t;
  const float* wp = Wb2 + (size_t)(kc * 256) * C + j;
  float acc = 0.f;
  #pragma unroll 8
  for (int kk = 0; kk < 256; ++kk) acc = fmaf(sh[kk], wp[(size_t)kk * C], acc);
  lpart[(size_t)kc * C + j] = acc;
}

// sum 4 lparts + bb2 -> logits; softmax -> belief
__global__ void k_logits_softmax(const float* __restrict__ lpart, const float* __restrict__ bb2,
                                 float* __restrict__ belief) {
  __shared__ float sl[C];
  __shared__ float red[4], redz[4];
  int t = threadIdx.x, w = t >> 6, lane = t & 63;
  for (int j = t; j < C; j += 256) {
    float v = bb2[j];
    #pragma unroll
    for (int p = 0; p < 4; ++p) v += lpart[(size_t)p * C + j];
    sl[j] = v;
  }
  __syncthreads();
  float m = -3.4e38f;
  for (int j = t; j < C; j += 256) m = fmaxf(m, sl[j]);
  m = wave_reduce_max(m);
  if (lane == 0) red[w] = m;
  __syncthreads();
  m = fmaxf(fmaxf(red[0], red[1]), fmaxf(red[2], red[3]));
  float z = 0.f;
  for (int j = t; j < C; j += 256) z += expf(sl[j] - m);
  z = wave_reduce_sum(z);
  if (lane == 0) redz[w] = z;
  __syncthreads();
  z = redz[0] + redz[1] + redz[2] + redz[3];
  float inv = 1.f / z;
  for (int j = t; j < C; j += 256) belief[j] = expf(sl[j] - m) * inv;
}

// ---- bf16 operand prep for the transition GEMM ----
// wt2t[j][k] = bf16(Wt2[k][j])   (C x NODE)
__global__ void k_cvt_wt2t(const float* __restrict__ Wt2, u16* __restrict__ wt2t) {
  __shared__ float sm[32][33];
  int tx = threadIdx.x & 31, ty = threadIdx.x >> 5;   // 32 x 8
  int jb = blockIdx.x * 32, kb = blockIdx.y * 32;
  #pragma unroll
  for (int r = 0; r < 4; ++r)
    sm[ty + r * 8][tx] = Wt2[(size_t)(kb + ty + r * 8) * C + jb + tx];
  __syncthreads();
  #pragma unroll
  for (int r = 0; r < 4; ++r)
    wt2t[(size_t)(jb + ty + r * 8) * NODE + kb + tx] = f2bf(sm[tx][ty + r * 8]);
}

// hiddenb[s][i][n] = bf16(relu(Wt1[i][n] + a_s*Wt1[C][n] + bt1[n]))
__global__ void k_cvt_hidden(const float* __restrict__ Wt1, const float* __restrict__ bt1,
                             const float* __restrict__ actions, u16* __restrict__ hiddenb) {
  int s = blockIdx.y;
  int i = blockIdx.x;
  int n = threadIdx.x * 4;
  float a_s = actions[s];
  const float4 wv = *(const float4*)&Wt1[(size_t)i * NODE + n];
  const float4 wa = *(const float4*)&Wt1[(size_t)C * NODE + n];
  const float4 bv = *(const float4*)&bt1[n];
  u16x4 o;
  o.x = f2bf(fmaxf(fmaf(a_s, wa.x, wv.x) + bv.x, 0.f));
  o.y = f2bf(fmaxf(fmaf(a_s, wa.y, wv.y) + bv.y, 0.f));
  o.z = f2bf(fmaxf(fmaf(a_s, wa.z, wv.z) + bv.z, 0.f));
  o.w = f2bf(fmaxf(fmaf(a_s, wa.w, wv.w) + bv.w, 0.f));
  *(u16x4*)&hiddenb[((size_t)s * C + i) * NODE + n] = o;
}

// ---- MFMA GEMM: logits = Ab(M=gg*C x K=NODE) * Bt^T(N=C x K=NODE) + bt2, bf16 out ----
__global__ __launch_bounds__(256) void k_trans_gemm(
    const u16* __restrict__ Ab, const u16* __restrict__ Bt,
    const float* __restrict__ bt2, u16* __restrict__ outb) {
  __shared__ u16 As[128 * 32];   // [row][k], 64 B rows
  __shared__ u16 Bs[128 * 32];   // [n][k]
  int tid = threadIdx.x;
  int lane = tid & 63;
  int w = tid >> 6;
  int quad = lane >> 4;
  int l16 = lane & 15;
  int r0 = blockIdx.y * 128;     // group-local row
  int c0 = blockIdx.x * 128;
  int wr = (w >> 1) * 64;
  int wc = (w & 1) * 64;

  f32x4 acc[4][4] = {};

  const u16* Ag = Ab + (size_t)(r0 + w * 32 + (lane >> 2)) * NODE + (lane & 3) * 8;
  const u16* Bg = Bt + (size_t)(c0 + w * 32 + (lane >> 2)) * NODE + (lane & 3) * 8;
  u16* AsW = &As[(w * 32) * 32];
  u16* BsW = &Bs[(w * 32) * 32];

  for (int k0 = 0; k0 < NODE; k0 += 32) {
    GLOAD_LDS16(Ag + k0, AsW);
    GLOAD_LDS16(Ag + (size_t)16 * NODE + k0, AsW + 16 * 32);
    GLOAD_LDS16(Bg + k0, BsW);
    GLOAD_LDS16(Bg + (size_t)16 * NODE + k0, BsW + 16 * 32);
    __syncthreads();
    short8 af[4], bfr[4];
    #pragma unroll
    for (int rt = 0; rt < 4; ++rt)
      af[rt] = *(const short8*)&As[(wr + rt * 16 + l16) * 32 + quad * 8];
    #pragma unroll
    for (int ct = 0; ct < 4; ++ct)
      bfr[ct] = *(const short8*)&Bs[(wc + ct * 16 + l16) * 32 + quad * 8];
    #pragma unroll
    for (int rt = 0; rt < 4; ++rt)
      #pragma unroll
      for (int ct = 0; ct < 4; ++ct)
        acc[rt][ct] = __builtin_amdgcn_mfma_f32_16x16x32_bf16(af[rt], bfr[ct], acc[rt][ct], 0, 0, 0);
    __syncthreads();
  }
  #pragma unroll
  for (int rt = 0; rt < 4; ++rt) {
    int rbase = r0 + wr + rt * 16 + quad * 4;
    #pragma unroll
    for (int ct = 0; ct < 4; ++ct) {
      int col = c0 + wc + ct * 16 + l16;
      float bias = bt2[col];
      #pragma unroll
      for (int rg = 0; rg < 4; ++rg)
        outb[(size_t)(rbase + rg) * C + col] = f2bf(acc[rt][ct][rg] + bias);
    }
  }
}

// per row: m = max_j l, Z = sum exp(l-m); store m and w = belief_{s-1}[i]/Z
__global__ void k_rowstats(const u16* __restrict__ logits, const float* __restrict__ beliefs,
                           int s0, float* __restrict__ rowm, float* __restrict__ roww) {
  int r = blockIdx.x * 4 + (threadIdx.x >> 6);   // group-local row
  int lane = threadIdx.x & 63;
  int s = s0 + (r >> 11);
  int i = r & (C - 1);
  const u16* lr = logits + (size_t)r * C;
  float m = -3.4e38f;
  for (int j = lane; j < C; j += 64) m = fmaxf(m, bf2f(lr[j]));
  m = wave_reduce_max(m);
  m = __shfl(m, 0, 64);
  float z = 0.f;
  for (int j = lane; j < C; j += 64) z += expf(bf2f(lr[j]) - m);
  z = wave_reduce_sum(z);
  if (lane == 0) {
    rowm[(size_t)s * C + i] = m;
    roww[(size_t)s * C + i] = beliefs[(size_t)s * C + i] / z;
  }
}

// partial pred over a 256-row chunk
__global__ void k_pred_partial(const u16* __restrict__ logits,
                               const float* __restrict__ rowm, const float* __restrict__ roww,
                               int s0, float* __restrict__ partial) {
  int t = threadIdx.x;
  int sl = blockIdx.z;
  int s = s0 + sl;
  int j = blockIdx.x * 256 + t;
  int i0 = blockIdx.y * 256;
  __shared__ float sm_[256], sw_[256];
  sm_[t] = rowm[(size_t)s * C + i0 + t];
  sw_[t] = roww[(size_t)s * C + i0 + t];
  __syncthreads();
  const u16* lp = logits + ((size_t)sl * C + i0) * C + j;
  float acc = 0.f;
  #pragma unroll 4
  for (int ii = 0; ii < 256; ++ii)
    acc += sw_[ii] * expf(bf2f(lp[(size_t)ii * C]) - sm_[ii]);
  partial[((size_t)s * 8 + blockIdx.y) * C + j] = acc;
}

__global__ void k_pred_reduce(const float* __restrict__ partial, float* __restrict__ pred) {
  int s = blockIdx.x >> 3;
  int j = ((blockIdx.x & 7) << 8) + threadIdx.x;
  float acc = 0.f;
  #pragma unroll
  for (int it = 0; it < 8; ++it) acc += partial[((size_t)s * 8 + it) * C + j];
  pred[(size_t)s * C + j] = acc;
}

__global__ void k_loss(const float* __restrict__ beliefs, const float* __restrict__ pred,
                       const float* __restrict__ obs_mean, const float* __restrict__ obs,
                       float* __restrict__ loss_out) {
  int s = blockIdx.x, t = threadIdx.x;
  float o = obs[s];
  float f = 0.f, sec = 0.f;
  for (int j = t; j < C; j += 256) {
    float b = beliefs[(size_t)(s + 1) * C + j];
    float d = o - obs_mean[j];
    float logp = -0.5f * d * d - 0.91893853320467274178f;
    f -= b * logp;
    float p = pred[(size_t)s * C + j];
    sec += (b > 0.f) ? b * (logf(b) - logf(p)) : 0.f;
  }
  __shared__ float rf[4], rs[4];
  int w = t >> 6, lane = t & 63;
  f = wave_reduce_sum(f);
  sec = wave_reduce_sum(sec);
  if (lane == 0) { rf[w] = f; rs[w] = sec; }
  __syncthreads();
  if (t == 0) {
    loss_out[s] = rf[0] + rf[1] + rf[2] + rf[3];
    loss_out[H + s] = rs[0] + rs[1] + rs[2] + rs[3];
  }
}

__global__ void k_final(const float* __restrict__ loss_out, const float* __restrict__ beliefs,
                        float* __restrict__ out) {
  int t = threadIdx.x;
  if (t == 0) {
    float tot = 0.f;
    for (int s = 0; s < H; ++s) tot += loss_out[s] + loss_out[H + s];
    out[0] = tot;
  }
  for (int j = t; j < C; j += 256) out[1 + j] = beliefs[(size_t)H * C + j];
}

extern "C" void kernel_launch(void* const* d_in, const int* in_sizes, int n_in,
                              void* d_out, int out_size, void* d_ws, size_t ws_size,
                              hipStream_t stream) {
  const float* obs         = (const float*)d_in[0];
  const float* actions     = (const float*)d_in[1];
  const float* prev_belief = (const float*)d_in[2];
  const float* Wb1 = (const float*)d_in[3];
  const float* bb1 = (const float*)d_in[4];
  const float* Wb2 = (const float*)d_in[5];
  const float* bb2 = (const float*)d_in[6];
  const float* Wt1 = (const float*)d_in[7];
  const float* bt1 = (const float*)d_in[8];
  const float* Wt2 = (const float*)d_in[9];
  const float* bt2 = (const float*)d_in[10];
  const float* Wo1 = (const float*)d_in[11];
  const float* bo1 = (const float*)d_in[12];
  const float* Wo2 = (const float*)d_in[13];
  const float* bo2 = (const float*)d_in[14];
  float* out = (float*)d_out;

  char* base = (char*)d_ws;
  size_t off = 0;
  auto alloc = [&](size_t bytes) {
    char* r = base + off;
    off = (off + bytes + 255) & ~(size_t)255;
    return r;
  };
  float* obs_mean = (float*)alloc((size_t)C * 4);
  float* beliefs  = (float*)alloc((size_t)(H + 1) * C * 4);
  float* hpart    = (float*)alloc((size_t)8 * NODE * 4);
  float* lpart    = (float*)alloc((size_t)4 * C * 4);
  float* rowm     = (float*)alloc((size_t)H * C * 4);
  float* roww     = (float*)alloc((size_t)H * C * 4);
  float* pred     = (float*)alloc((size_t)H * C * 4);
  float* partial  = (float*)alloc((size_t)H * 8 * C * 4);
  float* lossbuf  = (float*)alloc(64 * 4);
  u16* hiddenb    = (u16*)alloc((size_t)H * C * NODE * 2);
  u16* wt2t       = (u16*)alloc((size_t)C * NODE * 2);
  u16* logits_bf  = (u16*)(base + off);
  size_t rem = (ws_size > off) ? ws_size - off : 0;
  int g = (int)(rem / ((size_t)C * C * 2));
  if (g < 1) g = 1;
  if (g > H) g = H;

  k_obsmean<<<dim3(C / 4), 256, 0, stream>>>(Wo1, bo1, Wo2, bo2, obs_mean);
  hipMemcpyAsync(beliefs, prev_belief, (size_t)C * sizeof(float),
                 hipMemcpyDeviceToDevice, stream);
  k_cvt_wt2t<<<dim3(C / 32, NODE / 32), 256, 0, stream>>>(Wt2, wt2t);
  k_cvt_hidden<<<dim3(C, H), 256, 0, stream>>>(Wt1, bt1, actions, hiddenb);

  for (int s = 0; s < H; ++s) {
    k_hidden_part<<<dim3(NODE / 256, 8), 256, 0, stream>>>(beliefs + (size_t)s * C, Wb1, hpart);
    k_logits_part<<<dim3(C / 256, 4), 256, 0, stream>>>(hpart, Wb1, bb1, actions, obs, s,
                                                        Wb2, lpart);
    k_logits_softmax<<<1, 256, 0, stream>>>(lpart, bb2, beliefs + (size_t)(s + 1) * C);
  }

  for (int s0 = 0; s0 < H; s0 += g) {
    int gg = (H - s0 < g) ? (H - s0) : g;
    k_trans_gemm<<<dim3(C / 128, gg * (C / 128)), 256, 0, stream>>>(
        hiddenb + (size_t)s0 * C * NODE, wt2t, bt2, logits_bf);
    k_rowstats<<<dim3(gg * (C / 4)), 256, 0, stream>>>(logits_bf, beliefs, s0, rowm, roww);
    k_pred_partial<<<dim3(C / 256, C / 256, gg), 256, 0, stream>>>(logits_bf, rowm, roww, s0,
                                                                   partial);
  }
  k_pred_reduce<<<dim3(H * C / 256), 256, 0, stream>>>(partial, pred);
  k_loss<<<dim3(H), 256, 0, stream>>>(beliefs, pred, obs_mean, obs, lossbuf);
  k_final<<<1, 256, 0, stream>>>(lossbuf, beliefs, out);
}

// Round 3
// 445.711 us; speedup vs baseline: 3.9260x; 1.0974x over previous
//
#include <hip/hip_runtime.h>
#include <hip/hip_bf16.h>

#define C 2048
#define NODE 1024
#define H 8

typedef unsigned short u16;
typedef __attribute__((ext_vector_type(8))) short short8;
typedef __attribute__((ext_vector_type(4))) float f32x4;
typedef __attribute__((ext_vector_type(4))) unsigned short u16x4;
typedef __attribute__((ext_vector_type(8))) unsigned short u16x8;

static __device__ __forceinline__ float wave_reduce_sum(float v) {
  #pragma unroll
  for (int off = 32; off; off >>= 1) v += __shfl_down(v, off, 64);
  return v;
}
static __device__ __forceinline__ float wave_reduce_max(float v) {
  #pragma unroll
  for (int off = 32; off; off >>= 1) v = fmaxf(v, __shfl_down(v, off, 64));
  return v;
}
static __device__ __forceinline__ u16 f2bf(float x) {
  __hip_bfloat16 h = __float2bfloat16(x);
  return *reinterpret_cast<u16*>(&h);
}
static __device__ __forceinline__ float bf2f(u16 u) {
  unsigned v = ((unsigned)u) << 16;
  return __uint_as_float(v);
}

#define GLOAD_LDS16(g, l)                                                     \
  __builtin_amdgcn_global_load_lds(                                           \
      (const __attribute__((address_space(1))) void*)(g),                     \
      (__attribute__((address_space(3))) void*)(l), 16, 0, 0)

// obs_mean[i] = relu(Wo1[i,:] + bo1) . Wo2 + bo2   (one wave per row)
__global__ void k_obsmean(const float* __restrict__ Wo1, const float* __restrict__ bo1,
                          const float* __restrict__ Wo2, const float* __restrict__ bo2,
                          float* __restrict__ obs_mean) {
  int row = blockIdx.x * 4 + (threadIdx.x >> 6);
  int lane = threadIdx.x & 63;
  const float* wr = Wo1 + (size_t)row * NODE;
  float acc = 0.f;
  for (int n = lane; n < NODE; n += 64)
    acc += fmaxf(wr[n] + bo1[n], 0.f) * Wo2[n];
  acc = wave_reduce_sum(acc);
  if (lane == 0) obs_mean[row] = acc + bo2[0];
}

// elementwise fp32 -> bf16 for Wb1 rows [0,2048)
__global__ void k_cvt_wb1(const float* __restrict__ Wb1, u16* __restrict__ Wb1b) {
  size_t idx = ((size_t)blockIdx.x * 256 + threadIdx.x) * 4;
  const float4 v = *(const float4*)&Wb1[idx];
  u16x4 o;
  o.x = f2bf(v.x); o.y = f2bf(v.y); o.z = f2bf(v.z); o.w = f2bf(v.w);
  *(u16x4*)&Wb1b[idx] = o;
}

// transpose+convert: out[j][k] = bf16(in[k][j]), in is NODE x C
__global__ void k_cvt_wt2t(const float* __restrict__ Win, u16* __restrict__ outT) {
  __shared__ float sm[32][33];
  int tx = threadIdx.x & 31, ty = threadIdx.x >> 5;   // 32 x 8
  int jb = blockIdx.x * 32, kb = blockIdx.y * 32;
  #pragma unroll
  for (int r = 0; r < 4; ++r)
    sm[ty + r * 8][tx] = Win[(size_t)(kb + ty + r * 8) * C + jb + tx];
  __syncthreads();
  #pragma unroll
  for (int r = 0; r < 4; ++r)
    outT[(size_t)(jb + ty + r * 8) * NODE + kb + tx] = f2bf(sm[tx][ty + r * 8]);
}

// ---- belief chain: 2 kernels/step ----
// K1: (optionally) softmax(logits_prev) -> belief_s; then split-K partial of
// hidden: hpart[kc][n] = sum_{k in chunk} bel[k]*Wb1b[k][n]
// grid (2, 32): nc in [0,2) over n (512 each, thread owns pair), kc in [0,32) over k (64 rows)
__global__ void k_bel_hidden(const float* __restrict__ logits_prev,
                             const float* __restrict__ bel0, int first,
                             const u16* __restrict__ Wb1b,
                             float* __restrict__ bel_out, float* __restrict__ hpart) {
  __shared__ float sl[C];
  __shared__ float sbel[64];
  __shared__ float red[4], redz[4];
  int t = threadIdx.x, w = t >> 6, lane = t & 63;
  int nc = blockIdx.x, kc = blockIdx.y;
  if (first) {
    if (t < 64) sbel[t] = bel0[kc * 64 + t];
    __syncthreads();
  } else {
    #pragma unroll
    for (int i = 0; i < 8; ++i) sl[t + i * 256] = logits_prev[t + i * 256];
    __syncthreads();
    float m = -3.4e38f;
    #pragma unroll
    for (int i = 0; i < 8; ++i) m = fmaxf(m, sl[t + i * 256]);
    m = wave_reduce_max(m);
    if (lane == 0) red[w] = m;
    __syncthreads();
    m = fmaxf(fmaxf(red[0], red[1]), fmaxf(red[2], red[3]));
    float z = 0.f;
    #pragma unroll
    for (int i = 0; i < 8; ++i) z += expf(sl[t + i * 256] - m);
    z = wave_reduce_sum(z);
    if (lane == 0) redz[w] = z;
    __syncthreads();
    float invz = 1.f / (redz[0] + redz[1] + redz[2] + redz[3]);
    if (t < 64) {
      float b = expf(sl[kc * 64 + t] - m) * invz;
      sbel[t] = b;
      if (nc == 0) bel_out[kc * 64 + t] = b;
    }
    __syncthreads();
  }
  int n0 = nc * 512 + 2 * t;
  const u16* wp = Wb1b + (size_t)(kc * 64) * NODE + n0;
  float ax = 0.f, ay = 0.f;
  #pragma unroll 8
  for (int r = 0; r < 64; ++r) {
    float b = sbel[r];
    unsigned pair = *(const unsigned*)&wp[(size_t)r * NODE];
    ax = fmaf(b, bf2f((u16)(pair & 0xffff)), ax);
    ay = fmaf(b, bf2f((u16)(pair >> 16)), ay);
  }
  hpart[(size_t)kc * NODE + n0] = ax;
  hpart[(size_t)kc * NODE + n0 + 1] = ay;
}

// K2: finalize hidden (redundant per block) + 32 columns of logits, complete.
// grid 64 blocks; logits_out[j] = relu_hidden . Wb2t[j,:] + bb2[j]
__global__ void k_bel_logits(const float* __restrict__ hpart, const float* __restrict__ Wb1,
                             const float* __restrict__ bb1,
                             const float* __restrict__ actions, const float* __restrict__ obs,
                             int s, const u16* __restrict__ Wb2t, const float* __restrict__ bb2,
                             float* __restrict__ logits_out) {
  __shared__ float sh[NODE];
  __shared__ float sred[256];
  int t = threadIdx.x;
  int jc = blockIdx.x;
  float a_s = actions[s], o_s = obs[s];
  #pragma unroll
  for (int i = 0; i < 4; ++i) {
    int n = t + i * 256;
    float h = bb1[n];
    #pragma unroll 8
    for (int kc = 0; kc < 32; ++kc) h += hpart[(size_t)kc * NODE + n];
    h = fmaf(a_s, Wb1[(size_t)C * NODE + n], h);
    h = fmaf(o_s, Wb1[(size_t)(C + 1) * NODE + n], h);
    sh[n] = fmaxf(h, 0.f);
  }
  __syncthreads();
  int j = jc * 32 + (t >> 3);
  int ks = (t & 7) * 128;
  const u16* wp = Wb2t + (size_t)j * NODE + ks;
  float acc = 0.f;
  #pragma unroll
  for (int kk = 0; kk < 128; kk += 8) {
    u16x8 wv = *(const u16x8*)&wp[kk];
    #pragma unroll
    for (int q = 0; q < 8; ++q) acc = fmaf(sh[ks + kk + q], bf2f(wv[q]), acc);
  }
  sred[t] = acc;
  __syncthreads();
  if (t < 32) {
    float a = 0.f;
    #pragma unroll
    for (int p = 0; p < 8; ++p) a += sred[t * 8 + p];
    logits_out[jc * 32 + t] = a + bb2[jc * 32 + t];
  }
}

// softmax of final logits -> beliefs[H]
__global__ void k_softmax_final(const float* __restrict__ logits, float* __restrict__ belief) {
  __shared__ float red[4], redz[4];
  int t = threadIdx.x, w = t >> 6, lane = t & 63;
  float m = -3.4e38f;
  for (int j = t; j < C; j += 256) m = fmaxf(m, logits[j]);
  m = wave_reduce_max(m);
  if (lane == 0) red[w] = m;
  __syncthreads();
  m = fmaxf(fmaxf(red[0], red[1]), fmaxf(red[2], red[3]));
  float z = 0.f;
  for (int j = t; j < C; j += 256) z += expf(logits[j] - m);
  z = wave_reduce_sum(z);
  if (lane == 0) redz[w] = z;
  __syncthreads();
  z = redz[0] + redz[1] + redz[2] + redz[3];
  float inv = 1.f / z;
  for (int j = t; j < C; j += 256) belief[j] = expf(logits[j] - m) * inv;
}

// hiddenb[s][i][n] = bf16(relu(Wt1[i][n] + a_s*Wt1[C][n] + bt1[n])) — one pass over Wt1
__global__ void k_cvt_hidden(const float* __restrict__ Wt1, const float* __restrict__ bt1,
                             const float* __restrict__ actions, u16* __restrict__ hiddenb) {
  int i = blockIdx.x;
  int n = threadIdx.x * 4;
  const float4 wv = *(const float4*)&Wt1[(size_t)i * NODE + n];
  const float4 wa = *(const float4*)&Wt1[(size_t)C * NODE + n];
  const float4 bv = *(const float4*)&bt1[n];
  #pragma unroll
  for (int s = 0; s < H; ++s) {
    float a_s = actions[s];
    u16x4 o;
    o.x = f2bf(fmaxf(fmaf(a_s, wa.x, wv.x) + bv.x, 0.f));
    o.y = f2bf(fmaxf(fmaf(a_s, wa.y, wv.y) + bv.y, 0.f));
    o.z = f2bf(fmaxf(fmaf(a_s, wa.z, wv.z) + bv.z, 0.f));
    o.w = f2bf(fmaxf(fmaf(a_s, wa.w, wv.w) + bv.w, 0.f));
    *(u16x4*)&hiddenb[((size_t)s * C + i) * NODE + n] = o;
  }
}

// ---- MFMA GEMM: logits = Ab(M=gg*C x K=NODE) * Bt^T(N=C x K=NODE) + bt2, bf16 out ----
// BK=64: 32 MFMA per barrier pair
__global__ __launch_bounds__(256) void k_trans_gemm(
    const u16* __restrict__ Ab, const u16* __restrict__ Bt,
    const float* __restrict__ bt2, u16* __restrict__ outb) {
  __shared__ u16 As[128 * 64];   // [row][k], 128 B rows
  __shared__ u16 Bs[128 * 64];   // [n][k]
  int tid = threadIdx.x;
  int lane = tid & 63;
  int w = tid >> 6;
  int quad = lane >> 4;
  int l16 = lane & 15;
  int r0 = blockIdx.y * 128;
  int c0 = blockIdx.x * 128;
  int wr = (w >> 1) * 64;
  int wc = (w & 1) * 64;

  f32x4 acc[4][4] = {};

  const u16* Ag = Ab + (size_t)(r0 + w * 32 + (lane >> 3)) * NODE + (lane & 7) * 8;
  const u16* Bg = Bt + (size_t)(c0 + w * 32 + (lane >> 3)) * NODE + (lane & 7) * 8;
  u16* AsW = &As[(w * 32) * 64];
  u16* BsW = &Bs[(w * 32) * 64];

  for (int k0 = 0; k0 < NODE; k0 += 64) {
    GLOAD_LDS16(Ag + k0, AsW);
    GLOAD_LDS16(Ag + k0 + (size_t)8 * NODE, AsW + 8 * 64);
    GLOAD_LDS16(Ag + k0 + (size_t)16 * NODE, AsW + 16 * 64);
    GLOAD_LDS16(Ag + k0 + (size_t)24 * NODE, AsW + 24 * 64);
    GLOAD_LDS16(Bg + k0, BsW);
    GLOAD_LDS16(Bg + k0 + (size_t)8 * NODE, BsW + 8 * 64);
    GLOAD_LDS16(Bg + k0 + (size_t)16 * NODE, BsW + 16 * 64);
    GLOAD_LDS16(Bg + k0 + (size_t)24 * NODE, BsW + 24 * 64);
    __syncthreads();
    short8 af[4][2], bfr[4][2];
    #pragma unroll
    for (int rt = 0; rt < 4; ++rt) {
      af[rt][0] = *(const short8*)&As[(wr + rt * 16 + l16) * 64 + quad * 8];
      af[rt][1] = *(const short8*)&As[(wr + rt * 16 + l16) * 64 + 32 + quad * 8];
    }
    #pragma unroll
    for (int ct = 0; ct < 4; ++ct) {
      bfr[ct][0] = *(const short8*)&Bs[(wc + ct * 16 + l16) * 64 + quad * 8];
      bfr[ct][1] = *(const short8*)&Bs[(wc + ct * 16 + l16) * 64 + 32 + quad * 8];
    }
    #pragma unroll
    for (int rt = 0; rt < 4; ++rt)
      #pragma unroll
      for (int ct = 0; ct < 4; ++ct) {
        acc[rt][ct] = __builtin_amdgcn_mfma_f32_16x16x32_bf16(af[rt][0], bfr[ct][0], acc[rt][ct], 0, 0, 0);
        acc[rt][ct] = __builtin_amdgcn_mfma_f32_16x16x32_bf16(af[rt][1], bfr[ct][1], acc[rt][ct], 0, 0, 0);
      }
    __syncthreads();
  }
  #pragma unroll
  for (int rt = 0; rt < 4; ++rt) {
    int rbase = r0 + wr + rt * 16 + quad * 4;
    #pragma unroll
    for (int ct = 0; ct < 4; ++ct) {
      int col = c0 + wc + ct * 16 + l16;
      float bias = bt2[col];
      #pragma unroll
      for (int rg = 0; rg < 4; ++rg)
        outb[(size_t)(rbase + rg) * C + col] = f2bf(acc[rt][ct][rg] + bias);
    }
  }
}

// per row: m = max_j l, Z = sum exp(l-m); store m and w = belief_{s-1}[i]/Z
__global__ void k_rowstats(const u16* __restrict__ logits, const float* __restrict__ beliefs,
                           int s0, float* __restrict__ rowm, float* __restrict__ roww) {
  int r = blockIdx.x * 4 + (threadIdx.x >> 6);   // group-local row
  int lane = threadIdx.x & 63;
  int s = s0 + (r >> 11);
  int i = r & (C - 1);
  const u16* lr = logits + (size_t)r * C;
  float m = -3.4e38f;
  for (int j = lane; j < C; j += 64) m = fmaxf(m, bf2f(lr[j]));
  m = wave_reduce_max(m);
  m = __shfl(m, 0, 64);
  float z = 0.f;
  for (int j = lane; j < C; j += 64) z += expf(bf2f(lr[j]) - m);
  z = wave_reduce_sum(z);
  if (lane == 0) {
    rowm[(size_t)s * C + i] = m;
    roww[(size_t)s * C + i] = beliefs[(size_t)s * C + i] / z;
  }
}

// partial pred over a 256-row chunk
__global__ void k_pred_partial(const u16* __restrict__ logits,
                               const float* __restrict__ rowm, const float* __restrict__ roww,
                               int s0, float* __restrict__ partial) {
  int t = threadIdx.x;
  int sl = blockIdx.z;
  int s = s0 + sl;
  int j = blockIdx.x * 256 + t;
  int i0 = blockIdx.y * 256;
  __shared__ float sm_[256], sw_[256];
  sm_[t] = rowm[(size_t)s * C + i0 + t];
  sw_[t] = roww[(size_t)s * C + i0 + t];
  __syncthreads();
  const u16* lp = logits + ((size_t)sl * C + i0) * C + j;
  float acc = 0.f;
  #pragma unroll 4
  for (int ii = 0; ii < 256; ++ii)
    acc += sw_[ii] * expf(bf2f(lp[(size_t)ii * C]) - sm_[ii]);
  partial[((size_t)s * 8 + blockIdx.y) * C + j] = acc;
}

__global__ void k_pred_reduce(const float* __restrict__ partial, float* __restrict__ pred) {
  int s = blockIdx.x >> 3;
  int j = ((blockIdx.x & 7) << 8) + threadIdx.x;
  float acc = 0.f;
  #pragma unroll
  for (int it = 0; it < 8; ++it) acc += partial[((size_t)s * 8 + it) * C + j];
  pred[(size_t)s * C + j] = acc;
}

__global__ void k_loss(const float* __restrict__ beliefs, const float* __restrict__ pred,
                       const float* __restrict__ obs_mean, const float* __restrict__ obs,
                       float* __restrict__ loss_out) {
  int s = blockIdx.x, t = threadIdx.x;
  float o = obs[s];
  float f = 0.f, sec = 0.f;
  for (int j = t; j < C; j += 256) {
    float b = beliefs[(size_t)(s + 1) * C + j];
    float d = o - obs_mean[j];
    float logp = -0.5f * d * d - 0.91893853320467274178f;
    f -= b * logp;
    float p = pred[(size_t)s * C + j];
    sec += (b > 0.f) ? b * (logf(b) - logf(p)) : 0.f;
  }
  __shared__ float rf[4], rs[4];
  int w = t >> 6, lane = t & 63;
  f = wave_reduce_sum(f);
  sec = wave_reduce_sum(sec);
  if (lane == 0) { rf[w] = f; rs[w] = sec; }
  __syncthreads();
  if (t == 0) {
    loss_out[s] = rf[0] + rf[1] + rf[2] + rf[3];
    loss_out[H + s] = rs[0] + rs[1] + rs[2] + rs[3];
  }
}

__global__ void k_final(const float* __restrict__ loss_out, const float* __restrict__ beliefs,
                        float* __restrict__ out) {
  int t = threadIdx.x;
  if (t == 0) {
    float tot = 0.f;
    for (int s = 0; s < H; ++s) tot += loss_out[s] + loss_out[H + s];
    out[0] = tot;
  }
  for (int j = t; j < C; j += 256) out[1 + j] = beliefs[(size_t)H * C + j];
}

extern "C" void kernel_launch(void* const* d_in, const int* in_sizes, int n_in,
                              void* d_out, int out_size, void* d_ws, size_t ws_size,
                              hipStream_t stream) {
  const float* obs         = (const float*)d_in[0];
  const float* actions     = (const float*)d_in[1];
  const float* prev_belief = (const float*)d_in[2];
  const float* Wb1 = (const float*)d_in[3];
  const float* bb1 = (const float*)d_in[4];
  const float* Wb2 = (const float*)d_in[5];
  const float* bb2 = (const float*)d_in[6];
  const float* Wt1 = (const float*)d_in[7];
  const float* bt1 = (const float*)d_in[8];
  const float* Wt2 = (const float*)d_in[9];
  const float* bt2 = (const float*)d_in[10];
  const float* Wo1 = (const float*)d_in[11];
  const float* bo1 = (const float*)d_in[12];
  const float* Wo2 = (const float*)d_in[13];
  const float* bo2 = (const float*)d_in[14];
  float* out = (float*)d_out;

  char* base = (char*)d_ws;
  size_t off = 0;
  auto alloc = [&](size_t bytes) {
    char* r = base + off;
    off = (off + bytes + 255) & ~(size_t)255;
    return r;
  };
  float* obs_mean   = (float*)alloc((size_t)C * 4);
  float* beliefs    = (float*)alloc((size_t)(H + 1) * C * 4);
  float* hpart      = (float*)alloc((size_t)32 * NODE * 4);
  float* logits_ch  = (float*)alloc((size_t)(H + 1) * C * 4);
  float* rowm       = (float*)alloc((size_t)H * C * 4);
  float* roww       = (float*)alloc((size_t)H * C * 4);
  float* pred       = (float*)alloc((size_t)H * C * 4);
  float* partial    = (float*)alloc((size_t)H * 8 * C * 4);
  float* lossbuf    = (float*)alloc(64 * 4);
  u16* hiddenb      = (u16*)alloc((size_t)H * C * NODE * 2);
  u16* wt2t         = (u16*)alloc((size_t)C * NODE * 2);
  u16* Wb1b         = (u16*)alloc((size_t)C * NODE * 2);
  u16* Wb2t         = (u16*)alloc((size_t)C * NODE * 2);
  u16* logits_bf    = (u16*)(base + off);
  size_t rem = (ws_size > off) ? ws_size - off : 0;
  int g = (int)(rem / ((size_t)C * C * 2));
  if (g < 1) g = 1;
  if (g > H) g = H;

  k_obsmean<<<dim3(C / 4), 256, 0, stream>>>(Wo1, bo1, Wo2, bo2, obs_mean);
  hipMemcpyAsync(beliefs, prev_belief, (size_t)C * sizeof(float),
                 hipMemcpyDeviceToDevice, stream);
  k_cvt_wt2t<<<dim3(C / 32, NODE / 32), 256, 0, stream>>>(Wt2, wt2t);
  k_cvt_wt2t<<<dim3(C / 32, NODE / 32), 256, 0, stream>>>(Wb2, Wb2t);
  k_cvt_wb1<<<dim3((C * NODE) / 1024), 256, 0, stream>>>(Wb1, Wb1b);
  k_cvt_hidden<<<dim3(C), 256, 0, stream>>>(Wt1, bt1, actions, hiddenb);

  for (int s = 0; s < H; ++s) {
    k_bel_hidden<<<dim3(2, 32), 256, 0, stream>>>(
        logits_ch + (size_t)s * C, beliefs, s == 0, Wb1b,
        beliefs + (size_t)s * C, hpart);
    k_bel_logits<<<dim3(64), 256, 0, stream>>>(hpart, Wb1, bb1, actions, obs, s,
                                               Wb2t, bb2, logits_ch + (size_t)(s + 1) * C);
  }
  k_softmax_final<<<1, 256, 0, stream>>>(logits_ch + (size_t)H * C, beliefs + (size_t)H * C);

  for (int s0 = 0; s0 < H; s0 += g) {
    int gg = (H - s0 < g) ? (H - s0) : g;
    k_trans_gemm<<<dim3(C / 128, gg * (C / 128)), 256, 0, stream>>>(
        hiddenb + (size_t)s0 * C * NODE, wt2t, bt2, logits_bf);
    k_rowstats<<<dim3(gg * (C / 4)), 256, 0, stream>>>(logits_bf, beliefs, s0, rowm, roww);
    k_pred_partial<<<dim3(C / 256, C / 256, gg), 256, 0, stream>>>(logits_bf, rowm, roww, s0,
                                                                   partial);
  }
  k_pred_reduce<<<dim3(H * C / 256), 256, 0, stream>>>(partial, pred);
  k_loss<<<dim3(H), 256, 0, stream>>>(beliefs, pred, obs_mean, obs, lossbuf);
  k_final<<<1, 256, 0, stream>>>(lossbuf, beliefs, out);
}

// Round 4
// 381.797 us; speedup vs baseline: 4.5832x; 1.1674x over previous
//
#include <hip/hip_runtime.h>
#include <hip/hip_bf16.h>

#define C 2048
#define NODE 1024
#define H 8

typedef unsigned short u16;
typedef __attribute__((ext_vector_type(8))) short short8;
typedef __attribute__((ext_vector_type(4))) float f32x4;
typedef __attribute__((ext_vector_type(4))) unsigned short u16x4;
typedef __attribute__((ext_vector_type(8))) unsigned short u16x8;

static __device__ __forceinline__ float wave_reduce_sum(float v) {
  #pragma unroll
  for (int off = 32; off; off >>= 1) v += __shfl_down(v, off, 64);
  return v;
}
static __device__ __forceinline__ float wave_reduce_max(float v) {
  #pragma unroll
  for (int off = 32; off; off >>= 1) v = fmaxf(v, __shfl_down(v, off, 64));
  return v;
}
static __device__ __forceinline__ u16 f2bf(float x) {
  __hip_bfloat16 h = __float2bfloat16(x);
  return *reinterpret_cast<u16*>(&h);
}
static __device__ __forceinline__ float bf2f(u16 u) {
  unsigned v = ((unsigned)u) << 16;
  return __uint_as_float(v);
}

#define GLOAD_LDS16(g, l)                                                     \
  __builtin_amdgcn_global_load_lds(                                           \
      (const __attribute__((address_space(1))) void*)(g),                     \
      (__attribute__((address_space(3))) void*)(l), 16, 0, 0)

__global__ void k_zero(float* __restrict__ p) {
  p[blockIdx.x * 256 + threadIdx.x] = 0.f;
}

// obs_mean[i] = relu(Wo1[i,:] + bo1) . Wo2 + bo2   (one wave per row)
__global__ void k_obsmean(const float* __restrict__ Wo1, const float* __restrict__ bo1,
                          const float* __restrict__ Wo2, const float* __restrict__ bo2,
                          float* __restrict__ obs_mean) {
  int row = blockIdx.x * 4 + (threadIdx.x >> 6);
  int lane = threadIdx.x & 63;
  const float* wr = Wo1 + (size_t)row * NODE;
  float acc = 0.f;
  for (int n = lane; n < NODE; n += 64)
    acc += fmaxf(wr[n] + bo1[n], 0.f) * Wo2[n];
  acc = wave_reduce_sum(acc);
  if (lane == 0) obs_mean[row] = acc + bo2[0];
}

// elementwise fp32 -> bf16 for Wb1 rows [0,2048)
__global__ void k_cvt_wb1(const float* __restrict__ Wb1, u16* __restrict__ Wb1b) {
  size_t idx = ((size_t)blockIdx.x * 256 + threadIdx.x) * 4;
  const float4 v = *(const float4*)&Wb1[idx];
  u16x4 o;
  o.x = f2bf(v.x); o.y = f2bf(v.y); o.z = f2bf(v.z); o.w = f2bf(v.w);
  *(u16x4*)&Wb1b[idx] = o;
}

// transpose+convert: out[j][k] = bf16(in[k][j]), in is NODE x C
__global__ void k_cvt_wt2t(const float* __restrict__ Win, u16* __restrict__ outT) {
  __shared__ float sm[32][33];
  int tx = threadIdx.x & 31, ty = threadIdx.x >> 5;   // 32 x 8
  int jb = blockIdx.x * 32, kb = blockIdx.y * 32;
  #pragma unroll
  for (int r = 0; r < 4; ++r)
    sm[ty + r * 8][tx] = Win[(size_t)(kb + ty + r * 8) * C + jb + tx];
  __syncthreads();
  #pragma unroll
  for (int r = 0; r < 4; ++r)
    outT[(size_t)(jb + ty + r * 8) * NODE + kb + tx] = f2bf(sm[tx][ty + r * 8]);
}

// ---- belief chain: 2 kernels/step (unchanged from round 3 — verified) ----
__global__ void k_bel_hidden(const float* __restrict__ logits_prev,
                             const float* __restrict__ bel0, int first,
                             const u16* __restrict__ Wb1b,
                             float* __restrict__ bel_out, float* __restrict__ hpart) {
  __shared__ float sl[C];
  __shared__ float sbel[64];
  __shared__ float red[4], redz[4];
  int t = threadIdx.x, w = t >> 6, lane = t & 63;
  int nc = blockIdx.x, kc = blockIdx.y;
  if (first) {
    if (t < 64) sbel[t] = bel0[kc * 64 + t];
    __syncthreads();
  } else {
    #pragma unroll
    for (int i = 0; i < 8; ++i) sl[t + i * 256] = logits_prev[t + i * 256];
    __syncthreads();
    float m = -3.4e38f;
    #pragma unroll
    for (int i = 0; i < 8; ++i) m = fmaxf(m, sl[t + i * 256]);
    m = wave_reduce_max(m);
    if (lane == 0) red[w] = m;
    __syncthreads();
    m = fmaxf(fmaxf(red[0], red[1]), fmaxf(red[2], red[3]));
    float z = 0.f;
    #pragma unroll
    for (int i = 0; i < 8; ++i) z += expf(sl[t + i * 256] - m);
    z = wave_reduce_sum(z);
    if (lane == 0) redz[w] = z;
    __syncthreads();
    float invz = 1.f / (redz[0] + redz[1] + redz[2] + redz[3]);
    if (t < 64) {
      float b = expf(sl[kc * 64 + t] - m) * invz;
      sbel[t] = b;
      if (nc == 0) bel_out[kc * 64 + t] = b;
    }
    __syncthreads();
  }
  int n0 = nc * 512 + 2 * t;
  const u16* wp = Wb1b + (size_t)(kc * 64) * NODE + n0;
  float ax = 0.f, ay = 0.f;
  #pragma unroll 8
  for (int r = 0; r < 64; ++r) {
    float b = sbel[r];
    unsigned pair = *(const unsigned*)&wp[(size_t)r * NODE];
    ax = fmaf(b, bf2f((u16)(pair & 0xffff)), ax);
    ay = fmaf(b, bf2f((u16)(pair >> 16)), ay);
  }
  hpart[(size_t)kc * NODE + n0] = ax;
  hpart[(size_t)kc * NODE + n0 + 1] = ay;
}

__global__ void k_bel_logits(const float* __restrict__ hpart, const float* __restrict__ Wb1,
                             const float* __restrict__ bb1,
                             const float* __restrict__ actions, const float* __restrict__ obs,
                             int s, const u16* __restrict__ Wb2t, const float* __restrict__ bb2,
                             float* __restrict__ logits_out) {
  __shared__ float sh[NODE];
  __shared__ float sred[256];
  int t = threadIdx.x;
  int jc = blockIdx.x;
  float a_s = actions[s], o_s = obs[s];
  #pragma unroll
  for (int i = 0; i < 4; ++i) {
    int n = t + i * 256;
    float h = bb1[n];
    #pragma unroll 8
    for (int kc = 0; kc < 32; ++kc) h += hpart[(size_t)kc * NODE + n];
    h = fmaf(a_s, Wb1[(size_t)C * NODE + n], h);
    h = fmaf(o_s, Wb1[(size_t)(C + 1) * NODE + n], h);
    sh[n] = fmaxf(h, 0.f);
  }
  __syncthreads();
  int j = jc * 32 + (t >> 3);
  int ks = (t & 7) * 128;
  const u16* wp = Wb2t + (size_t)j * NODE + ks;
  float acc = 0.f;
  #pragma unroll
  for (int kk = 0; kk < 128; kk += 8) {
    u16x8 wv = *(const u16x8*)&wp[kk];
    #pragma unroll
    for (int q = 0; q < 8; ++q) acc = fmaf(sh[ks + kk + q], bf2f(wv[q]), acc);
  }
  sred[t] = acc;
  __syncthreads();
  if (t < 32) {
    float a = 0.f;
    #pragma unroll
    for (int p = 0; p < 8; ++p) a += sred[t * 8 + p];
    logits_out[jc * 32 + t] = a + bb2[jc * 32 + t];
  }
}

__global__ void k_softmax_final(const float* __restrict__ logits, float* __restrict__ belief) {
  __shared__ float red[4], redz[4];
  int t = threadIdx.x, w = t >> 6, lane = t & 63;
  float m = -3.4e38f;
  for (int j = t; j < C; j += 256) m = fmaxf(m, logits[j]);
  m = wave_reduce_max(m);
  if (lane == 0) red[w] = m;
  __syncthreads();
  m = fmaxf(fmaxf(red[0], red[1]), fmaxf(red[2], red[3]));
  float z = 0.f;
  for (int j = t; j < C; j += 256) z += expf(logits[j] - m);
  z = wave_reduce_sum(z);
  if (lane == 0) redz[w] = z;
  __syncthreads();
  z = redz[0] + redz[1] + redz[2] + redz[3];
  float inv = 1.f / z;
  for (int j = t; j < C; j += 256) belief[j] = expf(logits[j] - m) * inv;
}

// hiddenb[s][i][n] = bf16(relu(Wt1[i][n] + a_s*Wt1[C][n] + bt1[n])) — one pass over Wt1
__global__ void k_cvt_hidden(const float* __restrict__ Wt1, const float* __restrict__ bt1,
                             const float* __restrict__ actions, u16* __restrict__ hiddenb) {
  int i = blockIdx.x;
  int n = threadIdx.x * 4;
  const float4 wv = *(const float4*)&Wt1[(size_t)i * NODE + n];
  const float4 wa = *(const float4*)&Wt1[(size_t)C * NODE + n];
  const float4 bv = *(const float4*)&bt1[n];
  #pragma unroll
  for (int s = 0; s < H; ++s) {
    float a_s = actions[s];
    u16x4 o;
    o.x = f2bf(fmaxf(fmaf(a_s, wa.x, wv.x) + bv.x, 0.f));
    o.y = f2bf(fmaxf(fmaf(a_s, wa.y, wv.y) + bv.y, 0.f));
    o.z = f2bf(fmaxf(fmaf(a_s, wa.z, wv.z) + bv.z, 0.f));
    o.w = f2bf(fmaxf(fmaf(a_s, wa.w, wv.w) + bv.w, 0.f));
    *(u16x4*)&hiddenb[((size_t)s * C + i) * NODE + n] = o;
  }
}

// ---- MFMA GEMM (BK=32, round-2 structure): writes E = bf16(exp(logit+bias)),
// and accumulates row sums of E into rowZ via atomics (no separate rowstats pass).
// Transition logits are O(1) (weights ~1/sqrt(fan_in)) so exp needs no max-shift.
__global__ __launch_bounds__(256) void k_trans_gemm(
    const u16* __restrict__ Ab, const u16* __restrict__ Bt,
    const float* __restrict__ bt2, int s0,
    u16* __restrict__ outE, float* __restrict__ rowZ) {
  __shared__ u16 As[128 * 32];   // [row][k], 64 B rows
  __shared__ u16 Bs[128 * 32];   // [n][k]
  int tid = threadIdx.x;
  int lane = tid & 63;
  int w = tid >> 6;
  int quad = lane >> 4;
  int l16 = lane & 15;
  int r0 = blockIdx.y * 128;     // group-local row
  int c0 = blockIdx.x * 128;
  int wr = (w >> 1) * 64;
  int wc = (w & 1) * 64;

  f32x4 acc[4][4] = {};

  const u16* Ag = Ab + (size_t)(r0 + w * 32 + (lane >> 2)) * NODE + (lane & 3) * 8;
  const u16* Bg = Bt + (size_t)(c0 + w * 32 + (lane >> 2)) * NODE + (lane & 3) * 8;
  u16* AsW = &As[(w * 32) * 32];
  u16* BsW = &Bs[(w * 32) * 32];

  for (int k0 = 0; k0 < NODE; k0 += 32) {
    GLOAD_LDS16(Ag + k0, AsW);
    GLOAD_LDS16(Ag + (size_t)16 * NODE + k0, AsW + 16 * 32);
    GLOAD_LDS16(Bg + k0, BsW);
    GLOAD_LDS16(Bg + (size_t)16 * NODE + k0, BsW + 16 * 32);
    __syncthreads();
    short8 af[4], bfr[4];
    #pragma unroll
    for (int rt = 0; rt < 4; ++rt)
      af[rt] = *(const short8*)&As[(wr + rt * 16 + l16) * 32 + quad * 8];
    #pragma unroll
    for (int ct = 0; ct < 4; ++ct)
      bfr[ct] = *(const short8*)&Bs[(wc + ct * 16 + l16) * 32 + quad * 8];
    #pragma unroll
    for (int rt = 0; rt < 4; ++rt)
      #pragma unroll
      for (int ct = 0; ct < 4; ++ct)
        acc[rt][ct] = __builtin_amdgcn_mfma_f32_16x16x32_bf16(af[rt], bfr[ct], acc[rt][ct], 0, 0, 0);
    __syncthreads();
  }

  float bias[4];
  #pragma unroll
  for (int ct = 0; ct < 4; ++ct) bias[ct] = bt2[c0 + wc + ct * 16 + l16];
  #pragma unroll
  for (int rt = 0; rt < 4; ++rt) {
    #pragma unroll
    for (int rg = 0; rg < 4; ++rg) {
      int row = r0 + wr + rt * 16 + quad * 4 + rg;
      float rsum = 0.f;
      #pragma unroll
      for (int ct = 0; ct < 4; ++ct) {
        float e = __expf(acc[rt][ct][rg] + bias[ct]);
        u16 v = f2bf(e);
        outE[(size_t)row * C + c0 + wc + ct * 16 + l16] = v;
        rsum += bf2f(v);   // Z from rounded values -> pred exactly normalized
      }
      #pragma unroll
      for (int m = 1; m < 16; m <<= 1) rsum += __shfl_xor(rsum, m, 64);
      if (l16 == 0)
        atomicAdd(&rowZ[(size_t)(s0 + (row >> 11)) * C + (row & (C - 1))], rsum);
    }
  }
}

// partial pred over a 256-row chunk: pure bf16 FMA (no exp)
__global__ void k_pred_partial(const u16* __restrict__ E, const float* __restrict__ beliefs,
                               const float* __restrict__ rowZ, int s0,
                               float* __restrict__ partial) {
  int t = threadIdx.x;
  int sl = blockIdx.z;
  int s = s0 + sl;
  int j = blockIdx.x * 512 + 2 * t;
  int i0 = blockIdx.y * 256;
  __shared__ float sw_[256];
  sw_[t] = beliefs[(size_t)s * C + i0 + t] / rowZ[(size_t)s * C + i0 + t];
  __syncthreads();
  const u16* lp = E + ((size_t)sl * C + i0) * C + j;
  float ax = 0.f, ay = 0.f;
  #pragma unroll 8
  for (int ii = 0; ii < 256; ++ii) {
    unsigned pair = *(const unsigned*)&lp[(size_t)ii * C];
    float wv = sw_[ii];
    ax = fmaf(wv, bf2f((u16)(pair & 0xffff)), ax);
    ay = fmaf(wv, bf2f((u16)(pair >> 16)), ay);
  }
  size_t base = ((size_t)s * 8 + blockIdx.y) * C + j;
  partial[base] = ax;
  partial[base + 1] = ay;
}

// per step: first = -sum_j b*logp ; second = sum_j b*(log b - log pred); pred reduced inline
__global__ void k_loss(const float* __restrict__ beliefs, const float* __restrict__ partial,
                       const float* __restrict__ obs_mean, const float* __restrict__ obs,
                       float* __restrict__ loss_out) {
  int s = blockIdx.x, t = threadIdx.x;
  float o = obs[s];
  float f = 0.f, sec = 0.f;
  for (int j = t; j < C; j += 256) {
    float b = beliefs[(size_t)(s + 1) * C + j];
    float d = o - obs_mean[j];
    float logp = -0.5f * d * d - 0.91893853320467274178f;
    f -= b * logp;
    float p = 0.f;
    #pragma unroll
    for (int it = 0; it < 8; ++it) p += partial[((size_t)s * 8 + it) * C + j];
    sec += (b > 0.f) ? b * (logf(b) - logf(p)) : 0.f;
  }
  __shared__ float rf[4], rs[4];
  int w = t >> 6, lane = t & 63;
  f = wave_reduce_sum(f);
  sec = wave_reduce_sum(sec);
  if (lane == 0) { rf[w] = f; rs[w] = sec; }
  __syncthreads();
  if (t == 0) {
    loss_out[s] = rf[0] + rf[1] + rf[2] + rf[3];
    loss_out[H + s] = rs[0] + rs[1] + rs[2] + rs[3];
  }
}

__global__ void k_final(const float* __restrict__ loss_out, const float* __restrict__ beliefs,
                        float* __restrict__ out) {
  int t = threadIdx.x;
  if (t == 0) {
    float tot = 0.f;
    for (int s = 0; s < H; ++s) tot += loss_out[s] + loss_out[H + s];
    out[0] = tot;
  }
  for (int j = t; j < C; j += 256) out[1 + j] = beliefs[(size_t)H * C + j];
}

extern "C" void kernel_launch(void* const* d_in, const int* in_sizes, int n_in,
                              void* d_out, int out_size, void* d_ws, size_t ws_size,
                              hipStream_t stream) {
  const float* obs         = (const float*)d_in[0];
  const float* actions     = (const float*)d_in[1];
  const float* prev_belief = (const float*)d_in[2];
  const float* Wb1 = (const float*)d_in[3];
  const float* bb1 = (const float*)d_in[4];
  const float* Wb2 = (const float*)d_in[5];
  const float* bb2 = (const float*)d_in[6];
  const float* Wt1 = (const float*)d_in[7];
  const float* bt1 = (const float*)d_in[8];
  const float* Wt2 = (const float*)d_in[9];
  const float* bt2 = (const float*)d_in[10];
  const float* Wo1 = (const float*)d_in[11];
  const float* bo1 = (const float*)d_in[12];
  const float* Wo2 = (const float*)d_in[13];
  const float* bo2 = (const float*)d_in[14];
  float* out = (float*)d_out;

  char* base = (char*)d_ws;
  size_t off = 0;
  auto alloc = [&](size_t bytes) {
    char* r = base + off;
    off = (off + bytes + 255) & ~(size_t)255;
    return r;
  };
  float* obs_mean   = (float*)alloc((size_t)C * 4);
  float* beliefs    = (float*)alloc((size_t)(H + 1) * C * 4);
  float* hpart      = (float*)alloc((size_t)32 * NODE * 4);
  float* logits_ch  = (float*)alloc((size_t)(H + 1) * C * 4);
  float* rowZ       = (float*)alloc((size_t)H * C * 4);
  float* partial    = (float*)alloc((size_t)H * 8 * C * 4);
  float* lossbuf    = (float*)alloc(64 * 4);
  u16* hiddenb      = (u16*)alloc((size_t)H * C * NODE * 2);
  u16* wt2t         = (u16*)alloc((size_t)C * NODE * 2);
  u16* Wb1b         = (u16*)alloc((size_t)C * NODE * 2);
  u16* Wb2t         = (u16*)alloc((size_t)C * NODE * 2);
  u16* E_bf         = (u16*)(base + off);
  size_t rem = (ws_size > off) ? ws_size - off : 0;
  int g = (int)(rem / ((size_t)C * C * 2));
  if (g < 1) g = 1;
  if (g > H) g = H;

  k_obsmean<<<dim3(C / 4), 256, 0, stream>>>(Wo1, bo1, Wo2, bo2, obs_mean);
  hipMemcpyAsync(beliefs, prev_belief, (size_t)C * sizeof(float),
                 hipMemcpyDeviceToDevice, stream);
  k_zero<<<dim3(H * C / 256), 256, 0, stream>>>(rowZ);
  k_cvt_wt2t<<<dim3(C / 32, NODE / 32), 256, 0, stream>>>(Wt2, wt2t);
  k_cvt_wt2t<<<dim3(C / 32, NODE / 32), 256, 0, stream>>>(Wb2, Wb2t);
  k_cvt_wb1<<<dim3((C * NODE) / 1024), 256, 0, stream>>>(Wb1, Wb1b);
  k_cvt_hidden<<<dim3(C), 256, 0, stream>>>(Wt1, bt1, actions, hiddenb);

  for (int s = 0; s < H; ++s) {
    k_bel_hidden<<<dim3(2, 32), 256, 0, stream>>>(
        logits_ch + (size_t)s * C, beliefs, s == 0, Wb1b,
        beliefs + (size_t)s * C, hpart);
    k_bel_logits<<<dim3(64), 256, 0, stream>>>(hpart, Wb1, bb1, actions, obs, s,
                                               Wb2t, bb2, logits_ch + (size_t)(s + 1) * C);
  }
  k_softmax_final<<<1, 256, 0, stream>>>(logits_ch + (size_t)H * C, beliefs + (size_t)H * C);

  for (int s0 = 0; s0 < H; s0 += g) {
    int gg = (H - s0 < g) ? (H - s0) : g;
    k_trans_gemm<<<dim3(C / 128, gg * (C / 128)), 256, 0, stream>>>(
        hiddenb + (size_t)s0 * C * NODE, wt2t, bt2, s0, E_bf, rowZ);
    k_pred_partial<<<dim3(C / 512, C / 256, gg), 256, 0, stream>>>(E_bf, beliefs, rowZ, s0,
                                                                   partial);
  }
  k_loss<<<dim3(H), 256, 0, stream>>>(beliefs, partial, obs_mean, obs, lossbuf);
  k_final<<<1, 256, 0, stream>>>(lossbuf, beliefs, out);
}